// Round 11
// baseline (44.746 us; speedup 1.0000x reference)
//
#include <hip/hip_runtime.h>

// out[b,k] = tanh( sum_{m in segment k} x[b,m] * w[m] ),  seg_ids sorted.
//
// R11: test the SECOND read path. All R2-R10 kernels served reads at
// 3.2-3.4 TB/s regardless of structure (VGPR-return float4 loads). This
// variant stages x via __builtin_amdgcn_global_load_lds (async DMA to LDS,
// no VGPR writeback) to test whether the ceiling is the vector-return path.
//  - Block = 4 waves x 8 rows; wave owns 2 rows + its private LDS rows and
//    slab rows -> per-wave vmcnt/lgkmcnt only, ZERO __syncthreads.
//  - Interleaved chunk mapping (lane ln, chunk i -> floats win*1024+i*256+ln*4):
//    gload_lds dest = base + lane*16 (linear, required) and ds_read_b128 at
//    lane*16 stride = conflict-baseline. ids/w loaded to VGPRs (L2-hot).
//  - STEP run-flush into per-row LDS slab (ds_add_f32); interior ids ->
//    tanh stores; window-edge ids -> carry; fixup merges edges AND zero-fills
//    gap/prefix ids (zero_out kernel folded in -> 2 dispatches total).

#define TPB   256
#define WIN   1024            // floats per window
#define ROWS  8               // batch rows per block (2 per wave)
#define SLOTS 192             // id-span capacity per window (span ~64±16)

__device__ __forceinline__ void gload_lds16(const float* g, void* l) {
    __builtin_amdgcn_global_load_lds(
        (const __attribute__((address_space(1))) void*)g,
        (__attribute__((address_space(3)))  void*)l,
        16, 0, 0);
}

__global__ __launch_bounds__(TPB) void seg_glds(
        const float* __restrict__ x,
        const float* __restrict__ w,
        const int*   __restrict__ ids,
        float* __restrict__ out,
        float* __restrict__ carry,
        int M, int K, int NW) {
    __shared__ float4 xstage[ROWS][WIN / 4];   // 32 KB
    __shared__ float  slab[ROWS][SLOTS];       // 6 KB

    const int ln   = threadIdx.x & 63;
    const int wv   = threadIdx.x >> 6;         // 0..3
    const int win  = blockIdx.x;
    const int r0   = blockIdx.y * ROWS;
    const int rowA = r0 + 2 * wv;
    const int rowB = rowA + 1;
    const int fb   = win * WIN + ln * 4;       // chunk-i float index adds i*256

    // ---- issue async global->LDS DMA for both rows (8 x 16B/lane) ----
    const float* ga = x + (size_t)rowA * M + fb;
    const float* gb = x + (size_t)rowB * M + fb;
    #pragma unroll
    for (int j = 0; j < 4; ++j)
        gload_lds16(ga + j * 256, (void*)&xstage[2 * wv + 0][j * 64]);
    #pragma unroll
    for (int j = 0; j < 4; ++j)
        gload_lds16(gb + j * 256, (void*)&xstage[2 * wv + 1][j * 64]);

    // ---- ids + w to VGPRs (same interleaved mapping), overlap with DMA ----
    int4   i0 = *reinterpret_cast<const int4*>(ids + fb);
    int4   i1 = *reinterpret_cast<const int4*>(ids + fb + 256);
    int4   i2 = *reinterpret_cast<const int4*>(ids + fb + 512);
    int4   i3 = *reinterpret_cast<const int4*>(ids + fb + 768);
    float4 q0 = *reinterpret_cast<const float4*>(w + fb);
    float4 q1 = *reinterpret_cast<const float4*>(w + fb + 256);
    float4 q2 = *reinterpret_cast<const float4*>(w + fb + 512);
    float4 q3 = *reinterpret_cast<const float4*>(w + fb + 768);

    // ---- zero my wave's slab rows while loads are in flight ----
    #pragma unroll
    for (int i = ln; i < 2 * SLOTS; i += 64)
        (&slab[2 * wv][0])[i] = 0.f;

    asm volatile("s_waitcnt vmcnt(0) lgkmcnt(0)" ::: "memory");
    __builtin_amdgcn_sched_barrier(0);

    const int firstId = __shfl(i0.x, 0);       // ids[win*WIN]
    const int lastId  = __shfl(i3.w, 63);      // ids[win*WIN + WIN-1]
    const int span    = min(lastId - firstId + 1, SLOTS);

    // ---- per row: ds_read_b128 chunks + run-flush into slab ----
    #pragma unroll
    for (int rr = 0; rr < 2; ++rr) {
        float* __restrict__ sl = slab[2 * wv + rr];
        float acc = 0.f;
        int prev = i0.x;
        #define STEP(idv, xv, wvv)                                     \
            if ((idv) != prev) {                                       \
                atomicAdd(&sl[min(prev - firstId, SLOTS - 1)], acc);   \
                acc = 0.f; prev = (idv);                               \
            }                                                          \
            acc = fmaf((xv), (wvv), acc);
        {
            float4 xq = xstage[2 * wv + rr][0 * 64 + ln];
            STEP(i0.x, xq.x, q0.x) STEP(i0.y, xq.y, q0.y)
            STEP(i0.z, xq.z, q0.z) STEP(i0.w, xq.w, q0.w)
        }
        {
            float4 xq = xstage[2 * wv + rr][1 * 64 + ln];
            STEP(i1.x, xq.x, q1.x) STEP(i1.y, xq.y, q1.y)
            STEP(i1.z, xq.z, q1.z) STEP(i1.w, xq.w, q1.w)
        }
        {
            float4 xq = xstage[2 * wv + rr][2 * 64 + ln];
            STEP(i2.x, xq.x, q2.x) STEP(i2.y, xq.y, q2.y)
            STEP(i2.z, xq.z, q2.z) STEP(i2.w, xq.w, q2.w)
        }
        {
            float4 xq = xstage[2 * wv + rr][3 * 64 + ln];
            STEP(i3.x, xq.x, q3.x) STEP(i3.y, xq.y, q3.y)
            STEP(i3.z, xq.z, q3.z) STEP(i3.w, xq.w, q3.w)
        }
        #undef STEP
        atomicAdd(&sl[min(prev - firstId, SLOTS - 1)], acc);
    }

    asm volatile("s_waitcnt lgkmcnt(0)" ::: "memory");
    __builtin_amdgcn_sched_barrier(0);

    // ---- writeback: interiors -> tanh store; window edges -> carry ----
    for (int i = ln; i < 2 * span; i += 64) {
        int rr  = (i >= span) ? 1 : 0;
        int s   = i - rr * span;
        int id  = firstId + s;
        int row = rr ? rowB : rowA;
        float v = slab[2 * wv + rr][s];
        if (s == 0)
            carry[((size_t)row * NW + win) * 2 + 0] = v;
        else if (id == lastId)
            carry[((size_t)row * NW + win) * 2 + 1] = v;
        else
            out[(size_t)row * K + id] = tanhf(v);
    }
}

__global__ __launch_bounds__(TPB) void seg_fixup(
        const int*   __restrict__ ids,
        const float* __restrict__ carry,
        float* __restrict__ out,
        int K, int NW, int B) {
    int t = blockIdx.x * blockDim.x + threadIdx.x;
    if (t >= B * NW) return;
    int row = t / NW;
    int win = t - row * NW;

    int firstId = ids[win * WIN];
    int lastId  = ids[win * WIN + WIN - 1];
    float cF = carry[((size_t)row * NW + win) * 2 + 0];
    float cL = carry[((size_t)row * NW + win) * 2 + 1];

    // first id: complete here unless shared with previous window
    int prevLast = (win > 0) ? ids[win * WIN - 1] : -1;
    if (prevLast != firstId)
        out[(size_t)row * K + firstId] = tanhf(cF);

    // last id: owner of the (win, win+1) boundary merge
    int nextFirst = (win + 1 < NW) ? ids[(win + 1) * WIN] : K;
    float tot = cL;
    if (nextFirst == lastId)
        tot += carry[((size_t)row * NW + win + 1) * 2 + 0];
    out[(size_t)row * K + lastId] = tanhf(tot);

    // zero-fill empty segments owned by no window (gaps + global prefix)
    for (int id = lastId + 1; id < nextFirst; ++id)
        out[(size_t)row * K + id] = 0.f;
    if (win == 0)
        for (int id = 0; id < firstId; ++id)
            out[(size_t)row * K + id] = 0.f;
}

extern "C" void kernel_launch(void* const* d_in, const int* in_sizes, int n_in,
                              void* d_out, int out_size, void* d_ws, size_t ws_size,
                              hipStream_t stream) {
    const float* x       = (const float*)d_in[0];
    const float* w       = (const float*)d_in[1];
    const int*   seg_ids = (const int*)d_in[2];
    float* out = (float*)d_out;

    const int M = in_sizes[1];           // 65536
    const int B = in_sizes[0] / M;       // 256
    const int K = out_size / B;          // 4096
    const int NW = M / WIN;              // 64

    float* carry = (float*)d_ws;         // B*NW*2 floats = 128 KB

    dim3 grid(NW, B / ROWS);             // (64, 32) = 2048 blocks
    seg_glds<<<grid, TPB, 0, stream>>>(x, w, seg_ids, out, carry, M, K, NW);

    const int nfix = B * NW;             // 16384
    seg_fixup<<<(nfix + TPB - 1) / TPB, TPB, 0, stream>>>(seg_ids, carry, out, K, NW, B);
}